// Round 1
// baseline (845.298 us; speedup 1.0000x reference)
//
#include <hip/hip_runtime.h>
#include <hip/hip_bf16.h>
#include <math.h>

#define NEG_SLOPE 0.2f

// ---------------- wave helpers (wave = 64 lanes on gfx950) ----------------
__device__ inline float wave_sum(float v) {
#pragma unroll
    for (int d = 1; d < 64; d <<= 1) v += __shfl_xor(v, d);
    return v;
}
__device__ inline float wave_max(float v) {
#pragma unroll
    for (int d = 1; d < 64; d <<= 1) v = fmaxf(v, __shfl_xor(v, d));
    return v;
}
__device__ inline float lrelu(float v) { return v > 0.f ? v : NEG_SLOPE * v; }

// ---------------- CSR build ----------------
__global__ void count_deg_kernel(const int* __restrict__ ei, int E, int N,
                                 int* __restrict__ deg) {
    int e = blockIdx.x * blockDim.x + threadIdx.x;
    if (e >= E + N) return;
    int dst = (e < E) ? ei[E + e] : (e - E);   // row1 = dst; self-loops appended
    atomicAdd(&deg[dst], 1);
}

__global__ void scan_kernel(const int* __restrict__ deg, int* __restrict__ off, int N) {
    __shared__ int sums[1024];
    int tid = threadIdx.x;
    int chunk = (N + 1023) / 1024;
    int start = tid * chunk;
    int end = start + chunk; if (end > N) end = N;
    int s = 0;
    for (int i = start; i < end && i < N; i++) s += deg[i];
    sums[tid] = s;
    __syncthreads();
    for (int d = 1; d < 1024; d <<= 1) {
        int v = 0;
        if (tid >= d) v = sums[tid - d];
        __syncthreads();
        if (tid >= d) sums[tid] += v;
        __syncthreads();
    }
    int prefix = (tid == 0) ? 0 : sums[tid - 1];
    int run = prefix;
    for (int i = start; i < end && i < N; i++) { off[i] = run; run += deg[i]; }
    if (tid == 1023) off[N] = sums[1023];
}

__global__ void scatter_kernel(const int* __restrict__ ei, int E, int N,
                               const int* __restrict__ off, int* __restrict__ cursor,
                               int* __restrict__ csr_src) {
    int e = blockIdx.x * blockDim.x + threadIdx.x;
    if (e >= E + N) return;
    int src, dst;
    if (e < E) { src = ei[e]; dst = ei[E + e]; }
    else       { src = dst = e - E; }
    int pos = off[dst] + atomicAdd(&cursor[dst], 1);
    csr_src[pos] = src;
}

// ---------------- fp32 tiled GEMM: C[M,N] = A[M,K] @ B[K,N] ----------------
// BM=BN=64, BK=16, 256 threads, 4x4 per thread. N,K multiples of 64/16; M guarded.
__global__ __launch_bounds__(256) void gemm_f32(const float* __restrict__ A,
                                                const float* __restrict__ B,
                                                float* __restrict__ C,
                                                int M, int N, int K) {
    __shared__ float As[16][65];   // [k][m], +1 pad to kill write conflicts
    __shared__ float Bs[16][64];   // [k][n]
    int t  = threadIdx.x;
    int tx = t & 15;   // col group
    int ty = t >> 4;   // row group
    int rowBase = blockIdx.y * 64;
    int colBase = blockIdx.x * 64;
    float acc[4][4] = {{0.f}};
    for (int k0 = 0; k0 < K; k0 += 16) {
        {   // A tile 64x16
            int c  = t & 15;
            int r0 = t >> 4;
#pragma unroll
            for (int i = 0; i < 4; i++) {
                int r = r0 + i * 16;
                int grow = rowBase + r;
                float v = (grow < M) ? A[(size_t)grow * K + k0 + c] : 0.f;
                As[c][r] = v;
            }
        }
        {   // B tile 16x64
            int nloc = t & 63;
            int kloc = t >> 6;   // 0..3
#pragma unroll
            for (int i = 0; i < 4; i++) {
                int kk = kloc + i * 4;
                Bs[kk][nloc] = B[(size_t)(k0 + kk) * N + colBase + nloc];
            }
        }
        __syncthreads();
#pragma unroll
        for (int kk = 0; kk < 16; kk++) {
            float a[4], b[4];
#pragma unroll
            for (int i = 0; i < 4; i++) a[i] = As[kk][ty * 4 + i];
#pragma unroll
            for (int j = 0; j < 4; j++) b[j] = Bs[kk][tx * 4 + j];
#pragma unroll
            for (int i = 0; i < 4; i++)
#pragma unroll
                for (int j = 0; j < 4; j++) acc[i][j] += a[i] * b[j];
        }
        __syncthreads();
    }
#pragma unroll
    for (int i = 0; i < 4; i++) {
        int grow = rowBase + ty * 4 + i;
        if (grow < M) {
#pragma unroll
            for (int j = 0; j < 4; j++)
                C[(size_t)grow * N + colBase + tx * 4 + j] = acc[i][j];
        }
    }
}

// ---------------- attention logits: alS[n,h] = <h[n,h,:], a_src[h,:]> ----------------
template <int H, int C>
__global__ __launch_bounds__(256) void gat_alpha(const float* __restrict__ hbuf,
                                                 const float* __restrict__ a_src,
                                                 const float* __restrict__ a_dst,
                                                 float* __restrict__ alS,
                                                 float* __restrict__ alD, int N) {
    int gw = (blockIdx.x * blockDim.x + threadIdx.x) >> 6;  // global wave id
    int lane = threadIdx.x & 63;
    if (gw >= N * H) return;
    int n = gw / H, h = gw % H;
    const float* hp = hbuf + (size_t)n * H * C + h * C;
    float s = 0.f, d = 0.f;
#pragma unroll
    for (int c = lane; c < C; c += 64) {
        float v = hp[c];
        s += v * a_src[h * C + c];
        d += v * a_dst[h * C + c];
    }
    s = wave_sum(s);
    d = wave_sum(d);
    if (lane == 0) { alS[n * H + h] = s; alD[n * H + h] = d; }
}

// ---------------- segment softmax + aggregate, one wave per dst node ----------------
template <int H, int C>
__global__ __launch_bounds__(256) void gat_aggregate(const float* __restrict__ hbuf,
                                                     const float* __restrict__ alS,
                                                     const float* __restrict__ alD,
                                                     const int* __restrict__ off,
                                                     const int* __restrict__ csr_src,
                                                     const float* __restrict__ bias,
                                                     float* __restrict__ outbuf,
                                                     int N, int do_relu) {
    constexpr int HC = H * C;
    constexpr int PER = HC / 64;
    int n = (blockIdx.x * blockDim.x + threadIdx.x) >> 6;
    int lane = threadIdx.x & 63;
    if (n >= N) return;
    int beg = off[n], end = off[n + 1];

    float ad[H];
#pragma unroll
    for (int h = 0; h < H; h++) ad[h] = alD[n * H + h];

    // pass 1: max
    float m[H];
#pragma unroll
    for (int h = 0; h < H; h++) m[h] = -1e30f;
    for (int e = beg + lane; e < end; e += 64) {
        int s = csr_src[e];
#pragma unroll
        for (int h = 0; h < H; h++) {
            float v = lrelu(alS[s * H + h] + ad[h]);
            m[h] = fmaxf(m[h], v);
        }
    }
#pragma unroll
    for (int h = 0; h < H; h++) m[h] = wave_max(m[h]);

    // pass 2: denom
    float den[H];
#pragma unroll
    for (int h = 0; h < H; h++) den[h] = 0.f;
    for (int e = beg + lane; e < end; e += 64) {
        int s = csr_src[e];
#pragma unroll
        for (int h = 0; h < H; h++) {
            float v = lrelu(alS[s * H + h] + ad[h]);
            den[h] += __expf(v - m[h]);
        }
    }
    float inv[H];
#pragma unroll
    for (int h = 0; h < H; h++) inv[h] = 1.f / wave_sum(den[h]);

    // pass 3: weighted accumulate (all lanes walk edges together; lanes split channels)
    float acc[PER];
#pragma unroll
    for (int j = 0; j < PER; j++) acc[j] = 0.f;
    for (int e = beg; e < end; e++) {
        int s = csr_src[e];
        float w[H];
#pragma unroll
        for (int h = 0; h < H; h++) {
            float v = lrelu(alS[s * H + h] + ad[h]);
            w[h] = __expf(v - m[h]) * inv[h];
        }
        const float* hp = hbuf + (size_t)s * HC;
#pragma unroll
        for (int j = 0; j < PER; j++) {
            int c = j * 64 + lane;
            acc[j] += hp[c] * w[c / C];
        }
    }
    float* op = outbuf + (size_t)n * HC;
#pragma unroll
    for (int j = 0; j < PER; j++) {
        int c = j * 64 + lane;
        float v = acc[j] + bias[c];
        if (do_relu) v = fmaxf(v, 0.f);
        op[c] = v;
    }
}

// ---------------- risk head: sigmoid(relu(h@Ws1+bs1)@Ws2+bs2), wave per node ----------
__global__ __launch_bounds__(256) void head_kernel(const float* __restrict__ h3,
                                                   const float* __restrict__ Ws1,
                                                   const float* __restrict__ bs1,
                                                   const float* __restrict__ Ws2,
                                                   const float* __restrict__ bs2,
                                                   float* __restrict__ out, int N) {
    int n = (blockIdx.x * blockDim.x + threadIdx.x) >> 6;
    int lane = threadIdx.x & 63;
    if (n >= N) return;
    const float* hp = h3 + (size_t)n * 128;
    float s = bs1[lane];
#pragma unroll 8
    for (int k = 0; k < 128; k++) s += hp[k] * Ws1[k * 64 + lane];
    s = fmaxf(s, 0.f);
    float z = wave_sum(s * Ws2[lane]);
    if (lane == 0) out[n] = 1.f / (1.f + __expf(-(z + bs2[0])));
}

// ---------------- launch ----------------
extern "C" void kernel_launch(void* const* d_in, const int* in_sizes, int n_in,
                              void* d_out, int out_size, void* d_ws, size_t ws_size,
                              hipStream_t stream) {
    const float* x   = (const float*)d_in[0];
    const int*   ei  = (const int*)d_in[1];
    const float* W1  = (const float*)d_in[2];
    const float* as1 = (const float*)d_in[3];
    const float* ad1 = (const float*)d_in[4];
    const float* b1  = (const float*)d_in[5];
    const float* W2  = (const float*)d_in[6];
    const float* as2 = (const float*)d_in[7];
    const float* ad2 = (const float*)d_in[8];
    const float* b2  = (const float*)d_in[9];
    const float* W3  = (const float*)d_in[10];
    const float* as3 = (const float*)d_in[11];
    const float* ad3 = (const float*)d_in[12];
    const float* b3  = (const float*)d_in[13];
    const float* Ws1 = (const float*)d_in[14];
    const float* bs1 = (const float*)d_in[15];
    const float* Ws2 = (const float*)d_in[16];
    const float* bs2 = (const float*)d_in[17];

    const int N = out_size;            // 20000
    const int E = in_sizes[1] / 2;     // 160000
    const int D = in_sizes[0] / N;     // 768
    const int HC = 512, H = 4;
    const int Etot = E + N;

    // workspace carve-up
    char* p = (char*)d_ws;
    auto alloc = [&](size_t bytes) -> void* {
        void* q = (void*)p;
        p += (bytes + 255) & ~(size_t)255;
        return q;
    };
    int*   deg    = (int*)alloc((size_t)N * 4);
    int*   off    = (int*)alloc((size_t)(N + 1) * 4);
    int*   cursor = (int*)alloc((size_t)N * 4);
    int*   csr    = (int*)alloc((size_t)Etot * 4);
    float* alS    = (float*)alloc((size_t)N * H * 4);
    float* alD    = (float*)alloc((size_t)N * H * 4);
    float* bufA   = (float*)alloc((size_t)N * HC * 4);
    float* bufB   = (float*)alloc((size_t)N * HC * 4);

    hipMemsetAsync(deg, 0, (size_t)N * 4, stream);
    hipMemsetAsync(cursor, 0, (size_t)N * 4, stream);

    int tb = 256;
    count_deg_kernel<<<(Etot + tb - 1) / tb, tb, 0, stream>>>(ei, E, N, deg);
    scan_kernel<<<1, 1024, 0, stream>>>(deg, off, N);
    scatter_kernel<<<(Etot + tb - 1) / tb, tb, 0, stream>>>(ei, E, N, off, cursor, csr);

    dim3 g1(HC / 64, (N + 63) / 64);
    int alpha_blocks4 = (N * 4 + 3) / 4;   // 4 waves per 256-thread block
    int alpha_blocks1 = (N * 1 + 3) / 4;
    int node_blocks   = (N + 3) / 4;

    // ---- layer 1: x[N,768] @ W1[768,512] ----
    gemm_f32<<<g1, 256, 0, stream>>>(x, W1, bufA, N, HC, D);
    gat_alpha<4, 128><<<alpha_blocks4, 256, 0, stream>>>(bufA, as1, ad1, alS, alD, N);
    gat_aggregate<4, 128><<<node_blocks, 256, 0, stream>>>(bufA, alS, alD, off, csr, b1, bufB, N, 1);

    // ---- layer 2: bufB[N,512] @ W2[512,512] ----
    gemm_f32<<<g1, 256, 0, stream>>>(bufB, W2, bufA, N, HC, HC);
    gat_alpha<4, 128><<<alpha_blocks4, 256, 0, stream>>>(bufA, as2, ad2, alS, alD, N);
    gat_aggregate<4, 128><<<node_blocks, 256, 0, stream>>>(bufA, alS, alD, off, csr, b2, bufB, N, 1);

    // ---- layer 3: bufB[N,512] @ W3[512,128], H=1, no relu, no concat ----
    dim3 g3(128 / 64, (N + 63) / 64);
    gemm_f32<<<g3, 256, 0, stream>>>(bufB, W3, bufA, N, 128, HC);
    gat_alpha<1, 128><<<alpha_blocks1, 256, 0, stream>>>(bufA, as3, ad3, alS, alD, N);
    gat_aggregate<1, 128><<<node_blocks, 256, 0, stream>>>(bufA, alS, alD, off, csr, b3, bufB, N, 0);

    // ---- head ----
    head_kernel<<<node_blocks, 256, 0, stream>>>(bufB, Ws1, bs1, Ws2, bs2, (float*)d_out, N);
}

// Round 2
// 465.651 us; speedup vs baseline: 1.8153x; 1.8153x over previous
//
#include <hip/hip_runtime.h>
#include <hip/hip_bf16.h>
#include <math.h>

#define NEG_SLOPE 0.2f

typedef __attribute__((ext_vector_type(8))) __bf16 bf16x8;
typedef __attribute__((ext_vector_type(4))) float f32x4;

// ---------------- wave helpers (wave = 64 lanes on gfx950) ----------------
__device__ inline float wave_sum(float v) {
#pragma unroll
    for (int d = 1; d < 64; d <<= 1) v += __shfl_xor(v, d);
    return v;
}
__device__ inline float wave_max(float v) {
#pragma unroll
    for (int d = 1; d < 64; d <<= 1) v = fmaxf(v, __shfl_xor(v, d));
    return v;
}
__device__ inline float lrelu(float v) { return v > 0.f ? v : NEG_SLOPE * v; }

__device__ inline unsigned short f2bf(float f) {
    __hip_bfloat16 h = __float2bfloat16(f);
    return *reinterpret_cast<unsigned short*>(&h);
}

// ---------------- CSR build ----------------
__global__ void count_deg_kernel(const int* __restrict__ ei, int E, int N,
                                 int* __restrict__ deg) {
    int e = blockIdx.x * blockDim.x + threadIdx.x;
    if (e >= E + N) return;
    int dst = (e < E) ? ei[E + e] : (e - E);
    atomicAdd(&deg[dst], 1);
}

__global__ void scan_kernel(const int* __restrict__ deg, int* __restrict__ off, int N) {
    __shared__ int sums[1024];
    int tid = threadIdx.x;
    int chunk = (N + 1023) / 1024;
    int start = tid * chunk;
    int end = start + chunk; if (end > N) end = N;
    int s = 0;
    for (int i = start; i < end && i < N; i++) s += deg[i];
    sums[tid] = s;
    __syncthreads();
    for (int d = 1; d < 1024; d <<= 1) {
        int v = 0;
        if (tid >= d) v = sums[tid - d];
        __syncthreads();
        if (tid >= d) sums[tid] += v;
        __syncthreads();
    }
    int prefix = (tid == 0) ? 0 : sums[tid - 1];
    int run = prefix;
    for (int i = start; i < end && i < N; i++) { off[i] = run; run += deg[i]; }
    if (tid == 1023) off[N] = sums[1023];
}

__global__ void scatter_kernel(const int* __restrict__ ei, int E, int N,
                               const int* __restrict__ off, int* __restrict__ cursor,
                               int* __restrict__ csr_src) {
    int e = blockIdx.x * blockDim.x + threadIdx.x;
    if (e >= E + N) return;
    int src, dst;
    if (e < E) { src = ei[e]; dst = ei[E + e]; }
    else       { src = dst = e - E; }
    int pos = off[dst] + atomicAdd(&cursor[dst], 1);
    csr_src[pos] = src;
}

// ---------------- fp32 -> bf16 cast (vectorized), n % 4 == 0 ----------------
__global__ void cast_bf16_kernel(const float* __restrict__ in, unsigned short* __restrict__ out,
                                 size_t n4) {
    size_t i = (size_t)blockIdx.x * blockDim.x + threadIdx.x;
    if (i >= n4) return;
    float4 v = reinterpret_cast<const float4*>(in)[i];
    ushort4 o;
    o.x = f2bf(v.x); o.y = f2bf(v.y); o.z = f2bf(v.z); o.w = f2bf(v.w);
    reinterpret_cast<ushort4*>(out)[i] = o;
}

// ---------------- transpose-cast: out[n*K + k] = bf16(in[k*N + n]) ----------------
__global__ void transpose_cast_kernel(const float* __restrict__ in, unsigned short* __restrict__ out,
                                      int K, int N) {
    int idx = blockIdx.x * blockDim.x + threadIdx.x;
    if (idx >= K * N) return;
    int n = idx / K, k = idx % K;       // contiguous writes over k
    out[(size_t)n * K + k] = f2bf(in[(size_t)k * N + n]);
}

// ---------------- bf16 MFMA GEMM: C[M,N] = A[M,K] @ Bt[N,K]^T ----------------
// 128x128 tile, BK=32, 256 threads (4 waves, 2x2), 4x4 16x16x32 MFMA per wave.
// A,Bt bf16 row-major; C fp32. K % 32 == 0, N % 128 == 0; M guarded (staging clamps).
__global__ __launch_bounds__(256) void gemm_bf16(const unsigned short* __restrict__ A,
                                                 const unsigned short* __restrict__ Bt,
                                                 float* __restrict__ C,
                                                 int M, int N, int K) {
    __shared__ unsigned short Asl[128 * 32];
    __shared__ unsigned short Bsl[128 * 32];
    const int tid  = threadIdx.x;
    const int lane = tid & 63;
    const int wave = tid >> 6;
    const int rowBase = blockIdx.y * 128;
    const int colBase = blockIdx.x * 128;
    const int wm = (wave & 1) * 64;
    const int wn = (wave >> 1) * 64;
    const int q   = lane >> 4;   // 0..3
    const int l16 = lane & 15;

    f32x4 acc[4][4] = {};

    // staging slot for this thread: slot s covers row s>>2, cols (s&3)*8..+8
    for (int k0 = 0; k0 < K; k0 += 32) {
#pragma unroll
        for (int it = 0; it < 2; it++) {
            int s = it * 256 + tid;
            int r = s >> 2;
            int c = (s & 3) * 8;
            // A tile (row-clamped for M edge; clamped rows are never consumed)
            int ga = rowBase + r; if (ga >= M) ga = M - 1;
            const unsigned short* gpa = A + (size_t)ga * K + k0 + c;
            __builtin_amdgcn_global_load_lds(
                (const __attribute__((address_space(1))) void*)gpa,
                (__attribute__((address_space(3))) void*)&Asl[(size_t)(it * 256 + wave * 64) * 8],
                16, 0, 0);
            // B tile (N is a multiple of 128 -> always in bounds)
            const unsigned short* gpb = Bt + (size_t)(colBase + r) * K + k0 + c;
            __builtin_amdgcn_global_load_lds(
                (const __attribute__((address_space(1))) void*)gpb,
                (__attribute__((address_space(3))) void*)&Bsl[(size_t)(it * 256 + wave * 64) * 8],
                16, 0, 0);
        }
        __syncthreads();

        bf16x8 af[4], bf[4];
#pragma unroll
        for (int mi = 0; mi < 4; mi++)
            af[mi] = *reinterpret_cast<const bf16x8*>(&Asl[(wm + mi * 16 + l16) * 32 + q * 8]);
#pragma unroll
        for (int ni = 0; ni < 4; ni++)
            bf[ni] = *reinterpret_cast<const bf16x8*>(&Bsl[(wn + ni * 16 + l16) * 32 + q * 8]);
#pragma unroll
        for (int mi = 0; mi < 4; mi++)
#pragma unroll
            for (int ni = 0; ni < 4; ni++)
                acc[mi][ni] = __builtin_amdgcn_mfma_f32_16x16x32_bf16(af[mi], bf[ni], acc[mi][ni], 0, 0, 0);
        __syncthreads();
    }

    // C/D layout: row = q*4 + r, col = l16  (verified mapping)
#pragma unroll
    for (int mi = 0; mi < 4; mi++) {
#pragma unroll
        for (int r = 0; r < 4; r++) {
            int grow = rowBase + wm + mi * 16 + q * 4 + r;
            if (grow < M) {
#pragma unroll
                for (int ni = 0; ni < 4; ni++) {
                    int gcol = colBase + wn + ni * 16 + l16;
                    C[(size_t)grow * N + gcol] = acc[mi][ni][r];
                }
            }
        }
    }
}

// ---------------- attention logits ----------------
template <int H, int C>
__global__ __launch_bounds__(256) void gat_alpha(const float* __restrict__ hbuf,
                                                 const float* __restrict__ a_src,
                                                 const float* __restrict__ a_dst,
                                                 float* __restrict__ alS,
                                                 float* __restrict__ alD, int N) {
    int gw = (blockIdx.x * blockDim.x + threadIdx.x) >> 6;
    int lane = threadIdx.x & 63;
    if (gw >= N * H) return;
    int n = gw / H, h = gw % H;
    const float* hp = hbuf + (size_t)n * H * C + h * C;
    float s = 0.f, d = 0.f;
#pragma unroll
    for (int c = lane; c < C; c += 64) {
        float v = hp[c];
        s += v * a_src[h * C + c];
        d += v * a_dst[h * C + c];
    }
    s = wave_sum(s);
    d = wave_sum(d);
    if (lane == 0) { alS[n * H + h] = s; alD[n * H + h] = d; }
}

// ---------------- segment softmax + aggregate, one wave per dst node ----------------
// OUT_BF16: 1 -> out is unsigned short* (bf16, with relu); 0 -> float* (no relu unless do_relu)
template <int H, int C, int OUT_BF16>
__global__ __launch_bounds__(256) void gat_aggregate(const float* __restrict__ hbuf,
                                                     const float* __restrict__ alS,
                                                     const float* __restrict__ alD,
                                                     const int* __restrict__ off,
                                                     const int* __restrict__ csr_src,
                                                     const float* __restrict__ bias,
                                                     void* __restrict__ outbuf,
                                                     int N, int do_relu) {
    constexpr int HC = H * C;
    constexpr int PER = HC / 64;
    int n = (blockIdx.x * blockDim.x + threadIdx.x) >> 6;
    int lane = threadIdx.x & 63;
    if (n >= N) return;
    int beg = off[n], end = off[n + 1];

    float ad[H];
#pragma unroll
    for (int h = 0; h < H; h++) ad[h] = alD[n * H + h];

    float m[H];
#pragma unroll
    for (int h = 0; h < H; h++) m[h] = -1e30f;
    for (int e = beg + lane; e < end; e += 64) {
        int s = csr_src[e];
#pragma unroll
        for (int h = 0; h < H; h++) {
            float v = lrelu(alS[s * H + h] + ad[h]);
            m[h] = fmaxf(m[h], v);
        }
    }
#pragma unroll
    for (int h = 0; h < H; h++) m[h] = wave_max(m[h]);

    float den[H];
#pragma unroll
    for (int h = 0; h < H; h++) den[h] = 0.f;
    for (int e = beg + lane; e < end; e += 64) {
        int s = csr_src[e];
#pragma unroll
        for (int h = 0; h < H; h++) {
            float v = lrelu(alS[s * H + h] + ad[h]);
            den[h] += __expf(v - m[h]);
        }
    }
    float inv[H];
#pragma unroll
    for (int h = 0; h < H; h++) inv[h] = 1.f / wave_sum(den[h]);

    float acc[PER];
#pragma unroll
    for (int j = 0; j < PER; j++) acc[j] = 0.f;
    for (int e = beg; e < end; e++) {
        int s = csr_src[e];
        float w[H];
#pragma unroll
        for (int h = 0; h < H; h++) {
            float v = lrelu(alS[s * H + h] + ad[h]);
            w[h] = __expf(v - m[h]) * inv[h];
        }
        const float* hp = hbuf + (size_t)s * HC;
#pragma unroll
        for (int j = 0; j < PER; j++) {
            int c = j * 64 + lane;
            acc[j] += hp[c] * w[c / C];
        }
    }
#pragma unroll
    for (int j = 0; j < PER; j++) {
        int c = j * 64 + lane;
        float v = acc[j] + bias[c];
        if (do_relu) v = fmaxf(v, 0.f);
        if (OUT_BF16) ((unsigned short*)outbuf)[(size_t)n * HC + c] = f2bf(v);
        else          ((float*)outbuf)[(size_t)n * HC + c] = v;
    }
}

// ---------------- risk head ----------------
__global__ __launch_bounds__(256) void head_kernel(const float* __restrict__ h3,
                                                   const float* __restrict__ Ws1,
                                                   const float* __restrict__ bs1,
                                                   const float* __restrict__ Ws2,
                                                   const float* __restrict__ bs2,
                                                   float* __restrict__ out, int N) {
    int n = (blockIdx.x * blockDim.x + threadIdx.x) >> 6;
    int lane = threadIdx.x & 63;
    if (n >= N) return;
    const float* hp = h3 + (size_t)n * 128;
    float s = bs1[lane];
#pragma unroll 8
    for (int k = 0; k < 128; k++) s += hp[k] * Ws1[k * 64 + lane];
    s = fmaxf(s, 0.f);
    float z = wave_sum(s * Ws2[lane]);
    if (lane == 0) out[n] = 1.f / (1.f + __expf(-(z + bs2[0])));
}

// ---------------- launch ----------------
extern "C" void kernel_launch(void* const* d_in, const int* in_sizes, int n_in,
                              void* d_out, int out_size, void* d_ws, size_t ws_size,
                              hipStream_t stream) {
    const float* x   = (const float*)d_in[0];
    const int*   ei  = (const int*)d_in[1];
    const float* W1  = (const float*)d_in[2];
    const float* as1 = (const float*)d_in[3];
    const float* ad1 = (const float*)d_in[4];
    const float* b1  = (const float*)d_in[5];
    const float* W2  = (const float*)d_in[6];
    const float* as2 = (const float*)d_in[7];
    const float* ad2 = (const float*)d_in[8];
    const float* b2  = (const float*)d_in[9];
    const float* W3  = (const float*)d_in[10];
    const float* as3 = (const float*)d_in[11];
    const float* ad3 = (const float*)d_in[12];
    const float* b3  = (const float*)d_in[13];
    const float* Ws1 = (const float*)d_in[14];
    const float* bs1 = (const float*)d_in[15];
    const float* Ws2 = (const float*)d_in[16];
    const float* bs2 = (const float*)d_in[17];

    const int N = out_size;            // 20000
    const int E = in_sizes[1] / 2;     // 160000
    const int D = in_sizes[0] / N;     // 768
    const int HC = 512, H = 4, C = 128;
    const int Etot = E + N;

    char* p = (char*)d_ws;
    auto alloc = [&](size_t bytes) -> void* {
        void* q = (void*)p;
        p += (bytes + 255) & ~(size_t)255;
        return q;
    };
    int*   deg    = (int*)alloc((size_t)N * 4);
    int*   off    = (int*)alloc((size_t)(N + 1) * 4);
    int*   cursor = (int*)alloc((size_t)N * 4);
    int*   csr    = (int*)alloc((size_t)Etot * 4);
    float* alS    = (float*)alloc((size_t)N * H * 4);
    float* alD    = (float*)alloc((size_t)N * H * 4);
    float* hbuf   = (float*)alloc((size_t)N * HC * 4);        // GEMM output (fp32)
    float* o3     = (float*)alloc((size_t)N * C * 4);         // layer-3 output (fp32)
    unsigned short* xbf  = (unsigned short*)alloc((size_t)N * D * 2);
    unsigned short* obf  = (unsigned short*)alloc((size_t)N * HC * 2); // layer-1/2 outputs (bf16)
    unsigned short* W1t  = (unsigned short*)alloc((size_t)D * HC * 2);
    unsigned short* W2t  = (unsigned short*)alloc((size_t)HC * HC * 2);
    unsigned short* W3t  = (unsigned short*)alloc((size_t)HC * C * 2);

    hipMemsetAsync(deg, 0, (size_t)N * 4, stream);
    hipMemsetAsync(cursor, 0, (size_t)N * 4, stream);

    const int tb = 256;
    count_deg_kernel<<<(Etot + tb - 1) / tb, tb, 0, stream>>>(ei, E, N, deg);
    scan_kernel<<<1, 1024, 0, stream>>>(deg, off, N);
    scatter_kernel<<<(Etot + tb - 1) / tb, tb, 0, stream>>>(ei, E, N, off, cursor, csr);

    // casts / transposes
    {
        size_t n4 = (size_t)N * D / 4;
        cast_bf16_kernel<<<(int)((n4 + 255) / 256), 256, 0, stream>>>(x, xbf, n4);
        transpose_cast_kernel<<<(D * HC + 255) / 256, 256, 0, stream>>>(W1, W1t, D, HC);
        transpose_cast_kernel<<<(HC * HC + 255) / 256, 256, 0, stream>>>(W2, W2t, HC, HC);
        transpose_cast_kernel<<<(HC * C + 255) / 256, 256, 0, stream>>>(W3, W3t, HC, C);
    }

    int alpha_blocks4 = (N * 4 + 3) / 4;
    int alpha_blocks1 = (N * 1 + 3) / 4;
    int node_blocks   = (N + 3) / 4;
    int rowTiles = (N + 127) / 128;

    // ---- layer 1: xbf[N,768] @ W1t^T -> hbuf[N,512] ----
    gemm_bf16<<<dim3(HC / 128, rowTiles), 256, 0, stream>>>(xbf, W1t, hbuf, N, HC, D);
    gat_alpha<4, 128><<<alpha_blocks4, 256, 0, stream>>>(hbuf, as1, ad1, alS, alD, N);
    gat_aggregate<4, 128, 1><<<node_blocks, 256, 0, stream>>>(hbuf, alS, alD, off, csr, b1, obf, N, 1);

    // ---- layer 2: obf[N,512] @ W2t^T -> hbuf[N,512] ----
    gemm_bf16<<<dim3(HC / 128, rowTiles), 256, 0, stream>>>(obf, W2t, hbuf, N, HC, HC);
    gat_alpha<4, 128><<<alpha_blocks4, 256, 0, stream>>>(hbuf, as2, ad2, alS, alD, N);
    gat_aggregate<4, 128, 1><<<node_blocks, 256, 0, stream>>>(hbuf, alS, alD, off, csr, b2, obf, N, 1);

    // ---- layer 3: obf[N,512] @ W3t^T -> hbuf[N,128] (H=1) ----
    gemm_bf16<<<dim3(C / 128, rowTiles), 256, 0, stream>>>(obf, W3t, hbuf, N, C, HC);
    gat_alpha<1, 128><<<alpha_blocks1, 256, 0, stream>>>(hbuf, as3, ad3, alS, alD, N);
    gat_aggregate<1, 128, 0><<<node_blocks, 256, 0, stream>>>(hbuf, alS, alD, off, csr, b3, o3, N, 0);

    // ---- head ----
    head_kernel<<<node_blocks, 256, 0, stream>>>(o3, Ws1, bs1, Ws2, bs2, (float*)d_out, N);
}

// Round 3
// 409.037 us; speedup vs baseline: 2.0666x; 1.1384x over previous
//
#include <hip/hip_runtime.h>
#include <hip/hip_bf16.h>
#include <math.h>

#define NEG_SLOPE 0.2f

typedef __attribute__((ext_vector_type(8))) __bf16 bf16x8;
typedef __attribute__((ext_vector_type(4))) float f32x4;

// ---------------- helpers ----------------
__device__ inline float lrelu(float v) { return v > 0.f ? v : NEG_SLOPE * v; }

__device__ inline unsigned short f2bf(float f) {
    __hip_bfloat16 h = __float2bfloat16(f);
    return *reinterpret_cast<unsigned short*>(&h);
}
__device__ inline float bf_lo(unsigned u) { return __uint_as_float(u << 16); }
__device__ inline float bf_hi(unsigned u) { return __uint_as_float(u & 0xffff0000u); }

// ---------------- CSR build ----------------
__global__ void count_deg_kernel(const int* __restrict__ ei, int E, int N,
                                 int* __restrict__ deg) {
    int e = blockIdx.x * blockDim.x + threadIdx.x;
    if (e >= E + N) return;
    int dst = (e < E) ? ei[E + e] : (e - E);
    atomicAdd(&deg[dst], 1);
}

__global__ void scan_kernel(const int* __restrict__ deg, int* __restrict__ off, int N) {
    __shared__ int sums[1024];
    int tid = threadIdx.x;
    int chunk = (N + 1023) / 1024;
    int start = tid * chunk;
    int end = start + chunk; if (end > N) end = N;
    int s = 0;
    for (int i = start; i < end && i < N; i++) s += deg[i];
    sums[tid] = s;
    __syncthreads();
    for (int d = 1; d < 1024; d <<= 1) {
        int v = 0;
        if (tid >= d) v = sums[tid - d];
        __syncthreads();
        if (tid >= d) sums[tid] += v;
        __syncthreads();
    }
    int prefix = (tid == 0) ? 0 : sums[tid - 1];
    int run = prefix;
    for (int i = start; i < end && i < N; i++) { off[i] = run; run += deg[i]; }
    if (tid == 1023) off[N] = sums[1023];
}

__global__ void scatter_kernel(const int* __restrict__ ei, int E, int N,
                               const int* __restrict__ off, int* __restrict__ cursor,
                               int* __restrict__ csr_src) {
    int e = blockIdx.x * blockDim.x + threadIdx.x;
    if (e >= E + N) return;
    int src, dst;
    if (e < E) { src = ei[e]; dst = ei[E + e]; }
    else       { src = dst = e - E; }
    int pos = off[dst] + atomicAdd(&cursor[dst], 1);
    csr_src[pos] = src;
}

// ---------------- fp32 -> bf16 cast (vectorized), n % 4 == 0 ----------------
__global__ void cast_bf16_kernel(const float* __restrict__ in, unsigned short* __restrict__ out,
                                 size_t n4) {
    size_t i = (size_t)blockIdx.x * blockDim.x + threadIdx.x;
    if (i >= n4) return;
    float4 v = reinterpret_cast<const float4*>(in)[i];
    ushort4 o;
    o.x = f2bf(v.x); o.y = f2bf(v.y); o.z = f2bf(v.z); o.w = f2bf(v.w);
    reinterpret_cast<ushort4*>(out)[i] = o;
}

// ---------------- transpose-cast: out[n*K + k] = bf16(in[k*N + n]) ----------------
__global__ void transpose_cast_kernel(const float* __restrict__ in, unsigned short* __restrict__ out,
                                      int K, int N) {
    int idx = blockIdx.x * blockDim.x + threadIdx.x;
    if (idx >= K * N) return;
    int n = idx / K, k = idx % K;
    out[(size_t)n * K + k] = f2bf(in[(size_t)k * N + n]);
}

// ---------------- bf16 MFMA GEMM: C[M,N] = A[M,K] @ Bt[N,K]^T, bf16 out ----------------
__global__ __launch_bounds__(256) void gemm_bf16(const unsigned short* __restrict__ A,
                                                 const unsigned short* __restrict__ Bt,
                                                 unsigned short* __restrict__ C,
                                                 int M, int N, int K) {
    __shared__ unsigned short Asl[128 * 32];
    __shared__ unsigned short Bsl[128 * 32];
    const int tid  = threadIdx.x;
    const int lane = tid & 63;
    const int wave = tid >> 6;
    const int rowBase = blockIdx.y * 128;
    const int colBase = blockIdx.x * 128;
    const int wm = (wave & 1) * 64;
    const int wn = (wave >> 1) * 64;
    const int q   = lane >> 4;
    const int l16 = lane & 15;

    f32x4 acc[4][4] = {};

    for (int k0 = 0; k0 < K; k0 += 32) {
#pragma unroll
        for (int it = 0; it < 2; it++) {
            int s = it * 256 + tid;
            int r = s >> 2;
            int c = (s & 3) * 8;
            int ga = rowBase + r; if (ga >= M) ga = M - 1;
            const unsigned short* gpa = A + (size_t)ga * K + k0 + c;
            __builtin_amdgcn_global_load_lds(
                (const __attribute__((address_space(1))) void*)gpa,
                (__attribute__((address_space(3))) void*)&Asl[(size_t)(it * 256 + wave * 64) * 8],
                16, 0, 0);
            const unsigned short* gpb = Bt + (size_t)(colBase + r) * K + k0 + c;
            __builtin_amdgcn_global_load_lds(
                (const __attribute__((address_space(1))) void*)gpb,
                (__attribute__((address_space(3))) void*)&Bsl[(size_t)(it * 256 + wave * 64) * 8],
                16, 0, 0);
        }
        __syncthreads();

        bf16x8 af[4], bf[4];
#pragma unroll
        for (int mi = 0; mi < 4; mi++)
            af[mi] = *reinterpret_cast<const bf16x8*>(&Asl[(wm + mi * 16 + l16) * 32 + q * 8]);
#pragma unroll
        for (int ni = 0; ni < 4; ni++)
            bf[ni] = *reinterpret_cast<const bf16x8*>(&Bsl[(wn + ni * 16 + l16) * 32 + q * 8]);
#pragma unroll
        for (int mi = 0; mi < 4; mi++)
#pragma unroll
            for (int ni = 0; ni < 4; ni++)
                acc[mi][ni] = __builtin_amdgcn_mfma_f32_16x16x32_bf16(af[mi], bf[ni], acc[mi][ni], 0, 0, 0);
        __syncthreads();
    }

#pragma unroll
    for (int mi = 0; mi < 4; mi++) {
#pragma unroll
        for (int r = 0; r < 4; r++) {
            int grow = rowBase + wm + mi * 16 + q * 4 + r;
            if (grow < M) {
#pragma unroll
                for (int ni = 0; ni < 4; ni++) {
                    int gcol = colBase + wn + ni * 16 + l16;
                    C[(size_t)grow * N + gcol] = f2bf(acc[mi][ni][r]);
                }
            }
        }
    }
}

// ---------------- attention logits: one wave per node, bf16 h ----------------
// lane covers PER contiguous channels; reduce within LPH-lane head groups.
template <int H, int C>
__global__ __launch_bounds__(256) void gat_alpha(const unsigned short* __restrict__ hb,
                                                 const float* __restrict__ a_src,
                                                 const float* __restrict__ a_dst,
                                                 float* __restrict__ alS,
                                                 float* __restrict__ alD, int N) {
    constexpr int HC = H * C;
    constexpr int PER = HC / 64;
    constexpr int LPH = C / PER;   // lanes per head
    int n = (blockIdx.x * blockDim.x + threadIdx.x) >> 6;
    int lane = threadIdx.x & 63;
    if (n >= N) return;
    const int myh = (lane * PER) / C;
    const int cc  = (lane * PER) % C;
    const unsigned short* hp = hb + (size_t)n * HC + lane * PER;

    float hv[PER];
    if (PER == 8) {
        uint4 raw = *reinterpret_cast<const uint4*>(hp);
        hv[0] = bf_lo(raw.x); hv[1] = bf_hi(raw.x);
        hv[2] = bf_lo(raw.y); hv[3] = bf_hi(raw.y);
        hv[4] = bf_lo(raw.z); hv[5] = bf_hi(raw.z);
        hv[6] = bf_lo(raw.w); hv[7] = bf_hi(raw.w);
    } else {
        unsigned raw = *reinterpret_cast<const unsigned*>(hp);
        hv[0] = bf_lo(raw); hv[1] = bf_hi(raw);
    }
    float s = 0.f, d = 0.f;
#pragma unroll
    for (int j = 0; j < PER; j++) {
        s += hv[j] * a_src[myh * C + cc + j];
        d += hv[j] * a_dst[myh * C + cc + j];
    }
#pragma unroll
    for (int dd = 1; dd < LPH; dd <<= 1) {
        s += __shfl_xor(s, dd);
        d += __shfl_xor(d, dd);
    }
    if ((lane & (LPH - 1)) == 0) {
        alS[n * H + myh] = s;
        alD[n * H + myh] = d;
    }
}

// ---------------- segment softmax + aggregate, one wave per dst node, bf16 h ----------
template <int H, int C, int OUT_BF16>
__global__ __launch_bounds__(256) void gat_aggregate(const unsigned short* __restrict__ hb,
                                                     const float* __restrict__ alS,
                                                     const float* __restrict__ alD,
                                                     const int* __restrict__ off,
                                                     const int* __restrict__ csr_src,
                                                     const float* __restrict__ bias,
                                                     void* __restrict__ outbuf,
                                                     int N, int do_relu) {
    constexpr int HC = H * C;
    constexpr int PER = HC / 64;
    int n = (blockIdx.x * blockDim.x + threadIdx.x) >> 6;
    int lane = threadIdx.x & 63;
    if (n >= N) return;
    int beg = off[n], end = off[n + 1];

    float ad[H];
#pragma unroll
    for (int h = 0; h < H; h++) ad[h] = alD[n * H + h];

    // online softmax over this node's edges (lanes split edges)
    float m[H], den[H];
#pragma unroll
    for (int h = 0; h < H; h++) { m[h] = -1e30f; den[h] = 0.f; }
    for (int e = beg + lane; e < end; e += 64) {
        int s = csr_src[e];
        float av[H];
        if (H == 4) {
            float4 a4 = *reinterpret_cast<const float4*>(&alS[s * 4]);
            av[0] = a4.x; if (H > 1) { av[1] = a4.y; av[2] = a4.z; av[3] = a4.w; }
        } else {
            av[0] = alS[s * H];
        }
#pragma unroll
        for (int h = 0; h < H; h++) {
            float v = lrelu(av[h] + ad[h]);
            float nm = fmaxf(m[h], v);
            den[h] = den[h] * __expf(m[h] - nm) + __expf(v - nm);
            m[h] = nm;
        }
    }
#pragma unroll
    for (int dd = 1; dd < 64; dd <<= 1) {
#pragma unroll
        for (int h = 0; h < H; h++) {
            float om = __shfl_xor(m[h], dd);
            float od = __shfl_xor(den[h], dd);
            float nm = fmaxf(m[h], om);
            den[h] = den[h] * __expf(m[h] - nm) + od * __expf(om - nm);
            m[h] = nm;
        }
    }

    // this lane's channel block / head
    const int myh = (lane * PER) / C;
    const float mh  = m[myh];
    const float ih  = 1.f / den[myh];
    const float adh = ad[myh];

    float acc[PER];
#pragma unroll
    for (int j = 0; j < PER; j++) acc[j] = 0.f;

    for (int e = beg; e < end; e++) {
        int s = csr_src[e];
        float v = lrelu(alS[s * H + myh] + adh);
        float w = __expf(v - mh) * ih;
        const unsigned short* hp = hb + (size_t)s * HC + lane * PER;
        if (PER == 8) {
            uint4 raw = *reinterpret_cast<const uint4*>(hp);
            acc[0] += bf_lo(raw.x) * w; acc[1] += bf_hi(raw.x) * w;
            acc[2] += bf_lo(raw.y) * w; acc[3] += bf_hi(raw.y) * w;
            acc[4] += bf_lo(raw.z) * w; acc[5] += bf_hi(raw.z) * w;
            acc[6] += bf_lo(raw.w) * w; acc[7] += bf_hi(raw.w) * w;
        } else {
            unsigned raw = *reinterpret_cast<const unsigned*>(hp);
            acc[0] += bf_lo(raw) * w; acc[1] += bf_hi(raw) * w;
        }
    }

#pragma unroll
    for (int j = 0; j < PER; j++) {
        int c = lane * PER + j;
        float v = acc[j] + bias[c];
        if (do_relu) v = fmaxf(v, 0.f);
        if (OUT_BF16) ((unsigned short*)outbuf)[(size_t)n * HC + c] = f2bf(v);
        else          ((float*)outbuf)[(size_t)n * HC + c] = v;
    }
}

// ---------------- risk head ----------------
__global__ __launch_bounds__(256) void head_kernel(const float* __restrict__ h3,
                                                   const float* __restrict__ Ws1,
                                                   const float* __restrict__ bs1,
                                                   const float* __restrict__ Ws2,
                                                   const float* __restrict__ bs2,
                                                   float* __restrict__ out, int N) {
    int n = (blockIdx.x * blockDim.x + threadIdx.x) >> 6;
    int lane = threadIdx.x & 63;
    if (n >= N) return;
    const float* hp = h3 + (size_t)n * 128;
    float s = bs1[lane];
#pragma unroll 8
    for (int k = 0; k < 128; k++) s += hp[k] * Ws1[k * 64 + lane];
    s = fmaxf(s, 0.f);
    float z = s * Ws2[lane];
#pragma unroll
    for (int d = 1; d < 64; d <<= 1) z += __shfl_xor(z, d);
    if (lane == 0) out[n] = 1.f / (1.f + __expf(-(z + bs2[0])));
}

// ---------------- launch ----------------
extern "C" void kernel_launch(void* const* d_in, const int* in_sizes, int n_in,
                              void* d_out, int out_size, void* d_ws, size_t ws_size,
                              hipStream_t stream) {
    const float* x   = (const float*)d_in[0];
    const int*   ei  = (const int*)d_in[1];
    const float* W1  = (const float*)d_in[2];
    const float* as1 = (const float*)d_in[3];
    const float* ad1 = (const float*)d_in[4];
    const float* b1  = (const float*)d_in[5];
    const float* W2  = (const float*)d_in[6];
    const float* as2 = (const float*)d_in[7];
    const float* ad2 = (const float*)d_in[8];
    const float* b2  = (const float*)d_in[9];
    const float* W3  = (const float*)d_in[10];
    const float* as3 = (const float*)d_in[11];
    const float* ad3 = (const float*)d_in[12];
    const float* b3  = (const float*)d_in[13];
    const float* Ws1 = (const float*)d_in[14];
    const float* bs1 = (const float*)d_in[15];
    const float* Ws2 = (const float*)d_in[16];
    const float* bs2 = (const float*)d_in[17];

    const int N = out_size;            // 20000
    const int E = in_sizes[1] / 2;     // 160000
    const int D = in_sizes[0] / N;     // 768
    const int HC = 512, H = 4, C = 128;
    const int Etot = E + N;

    char* p = (char*)d_ws;
    auto alloc = [&](size_t bytes) -> void* {
        void* q = (void*)p;
        p += (bytes + 255) & ~(size_t)255;
        return q;
    };
    int*   deg    = (int*)alloc((size_t)N * 4);
    int*   off    = (int*)alloc((size_t)(N + 1) * 4);
    int*   cursor = (int*)alloc((size_t)N * 4);
    int*   csr    = (int*)alloc((size_t)Etot * 4);
    float* alS    = (float*)alloc((size_t)N * H * 4);
    float* alD    = (float*)alloc((size_t)N * H * 4);
    float* o3     = (float*)alloc((size_t)N * C * 4);
    unsigned short* hbuf = (unsigned short*)alloc((size_t)N * HC * 2); // GEMM out (bf16)
    unsigned short* xbf  = (unsigned short*)alloc((size_t)N * D * 2);
    unsigned short* obf  = (unsigned short*)alloc((size_t)N * HC * 2);
    unsigned short* W1t  = (unsigned short*)alloc((size_t)D * HC * 2);
    unsigned short* W2t  = (unsigned short*)alloc((size_t)HC * HC * 2);
    unsigned short* W3t  = (unsigned short*)alloc((size_t)HC * C * 2);

    hipMemsetAsync(deg, 0, (size_t)N * 4, stream);
    hipMemsetAsync(cursor, 0, (size_t)N * 4, stream);

    const int tb = 256;
    count_deg_kernel<<<(Etot + tb - 1) / tb, tb, 0, stream>>>(ei, E, N, deg);
    scan_kernel<<<1, 1024, 0, stream>>>(deg, off, N);
    scatter_kernel<<<(Etot + tb - 1) / tb, tb, 0, stream>>>(ei, E, N, off, cursor, csr);

    {
        size_t n4 = (size_t)N * D / 4;
        cast_bf16_kernel<<<(int)((n4 + 255) / 256), 256, 0, stream>>>(x, xbf, n4);
        transpose_cast_kernel<<<(D * HC + 255) / 256, 256, 0, stream>>>(W1, W1t, D, HC);
        transpose_cast_kernel<<<(HC * HC + 255) / 256, 256, 0, stream>>>(W2, W2t, HC, HC);
        transpose_cast_kernel<<<(HC * C + 255) / 256, 256, 0, stream>>>(W3, W3t, HC, C);
    }

    int node_blocks = (N + 3) / 4;     // one wave per node
    int rowTiles = (N + 127) / 128;

    // ---- layer 1 ----
    gemm_bf16<<<dim3(HC / 128, rowTiles), 256, 0, stream>>>(xbf, W1t, hbuf, N, HC, D);
    gat_alpha<4, 128><<<node_blocks, 256, 0, stream>>>(hbuf, as1, ad1, alS, alD, N);
    gat_aggregate<4, 128, 1><<<node_blocks, 256, 0, stream>>>(hbuf, alS, alD, off, csr, b1, obf, N, 1);

    // ---- layer 2 ----
    gemm_bf16<<<dim3(HC / 128, rowTiles), 256, 0, stream>>>(obf, W2t, hbuf, N, HC, HC);
    gat_alpha<4, 128><<<node_blocks, 256, 0, stream>>>(hbuf, as2, ad2, alS, alD, N);
    gat_aggregate<4, 128, 1><<<node_blocks, 256, 0, stream>>>(hbuf, alS, alD, off, csr, b2, obf, N, 1);

    // ---- layer 3 (H=1, C=128) ----
    gemm_bf16<<<dim3(C / 128, rowTiles), 256, 0, stream>>>(obf, W3t, hbuf, N, C, HC);
    gat_alpha<1, 128><<<node_blocks, 256, 0, stream>>>(hbuf, as3, ad3, alS, alD, N);
    gat_aggregate<1, 128, 0><<<node_blocks, 256, 0, stream>>>(hbuf, alS, alD, off, csr, b3, o3, N, 0);

    // ---- head ----
    head_kernel<<<node_blocks, 256, 0, stream>>>(o3, Ws1, bs1, Ws2, bs2, (float*)d_out, N);
}

// Round 4
// 388.195 us; speedup vs baseline: 2.1775x; 1.0537x over previous
//
#include <hip/hip_runtime.h>
#include <hip/hip_bf16.h>
#include <math.h>

#define NEG_SLOPE 0.2f

typedef __attribute__((ext_vector_type(8))) __bf16 bf16x8;
typedef __attribute__((ext_vector_type(4))) float f32x4;

// ---------------- helpers ----------------
__device__ inline float lrelu(float v) { return v > 0.f ? v : NEG_SLOPE * v; }

__device__ inline unsigned short f2bf(float f) {
    __hip_bfloat16 h = __float2bfloat16(f);
    return *reinterpret_cast<unsigned short*>(&h);
}
__device__ inline float bf_lo(unsigned u) { return __uint_as_float(u << 16); }
__device__ inline float bf_hi(unsigned u) { return __uint_as_float(u & 0xffff0000u); }

// ---------------- CSR build ----------------
__global__ void count_deg_kernel(const int* __restrict__ ei, int E, int N,
                                 int* __restrict__ deg) {
    int e = blockIdx.x * blockDim.x + threadIdx.x;
    if (e >= E + N) return;
    int dst = (e < E) ? ei[E + e] : (e - E);
    atomicAdd(&deg[dst], 1);
}

__global__ void scan_kernel(const int* __restrict__ deg, int* __restrict__ off, int N) {
    __shared__ int sums[1024];
    int tid = threadIdx.x;
    int chunk = (N + 1023) / 1024;
    int start = tid * chunk;
    int end = start + chunk; if (end > N) end = N;
    int s = 0;
    for (int i = start; i < end && i < N; i++) s += deg[i];
    sums[tid] = s;
    __syncthreads();
    for (int d = 1; d < 1024; d <<= 1) {
        int v = 0;
        if (tid >= d) v = sums[tid - d];
        __syncthreads();
        if (tid >= d) sums[tid] += v;
        __syncthreads();
    }
    int prefix = (tid == 0) ? 0 : sums[tid - 1];
    int run = prefix;
    for (int i = start; i < end && i < N; i++) { off[i] = run; run += deg[i]; }
    if (tid == 1023) off[N] = sums[1023];
}

__global__ void scatter_kernel(const int* __restrict__ ei, int E, int N,
                               const int* __restrict__ off, int* __restrict__ cursor,
                               int* __restrict__ csr_src) {
    int e = blockIdx.x * blockDim.x + threadIdx.x;
    if (e >= E + N) return;
    int src, dst;
    if (e < E) { src = ei[e]; dst = ei[E + e]; }
    else       { src = dst = e - E; }
    int pos = off[dst] + atomicAdd(&cursor[dst], 1);
    csr_src[pos] = src;
}

// ---------------- fp32 -> bf16 cast (vectorized), n % 4 == 0 ----------------
__global__ void cast_bf16_kernel(const float* __restrict__ in, unsigned short* __restrict__ out,
                                 size_t n4) {
    size_t i = (size_t)blockIdx.x * blockDim.x + threadIdx.x;
    if (i >= n4) return;
    float4 v = reinterpret_cast<const float4*>(in)[i];
    ushort4 o;
    o.x = f2bf(v.x); o.y = f2bf(v.y); o.z = f2bf(v.z); o.w = f2bf(v.w);
    reinterpret_cast<ushort4*>(out)[i] = o;
}

// ---------------- transpose-cast: out[n*K + k] = bf16(in[k*N + n]) ----------------
__global__ void transpose_cast_kernel(const float* __restrict__ in, unsigned short* __restrict__ out,
                                      int K, int N) {
    int idx = blockIdx.x * blockDim.x + threadIdx.x;
    if (idx >= K * N) return;
    int n = idx / K, k = idx % K;
    out[(size_t)n * K + k] = f2bf(in[(size_t)k * N + n]);
}

// ---------------- bf16 MFMA GEMM: C[M,N] = A[M,K] @ Bt[N,K]^T, bf16 out ----------------
__global__ __launch_bounds__(256) void gemm_bf16(const unsigned short* __restrict__ A,
                                                 const unsigned short* __restrict__ Bt,
                                                 unsigned short* __restrict__ C,
                                                 int M, int N, int K) {
    __shared__ unsigned short Asl[128 * 32];
    __shared__ unsigned short Bsl[128 * 32];
    const int tid  = threadIdx.x;
    const int lane = tid & 63;
    const int wave = tid >> 6;
    const int rowBase = blockIdx.y * 128;
    const int colBase = blockIdx.x * 128;
    const int wm = (wave & 1) * 64;
    const int wn = (wave >> 1) * 64;
    const int q   = lane >> 4;
    const int l16 = lane & 15;

    f32x4 acc[4][4] = {};

    for (int k0 = 0; k0 < K; k0 += 32) {
#pragma unroll
        for (int it = 0; it < 2; it++) {
            int s = it * 256 + tid;
            int r = s >> 2;
            int c = (s & 3) * 8;
            int ga = rowBase + r; if (ga >= M) ga = M - 1;
            const unsigned short* gpa = A + (size_t)ga * K + k0 + c;
            __builtin_amdgcn_global_load_lds(
                (const __attribute__((address_space(1))) void*)gpa,
                (__attribute__((address_space(3))) void*)&Asl[(size_t)(it * 256 + wave * 64) * 8],
                16, 0, 0);
            const unsigned short* gpb = Bt + (size_t)(colBase + r) * K + k0 + c;
            __builtin_amdgcn_global_load_lds(
                (const __attribute__((address_space(1))) void*)gpb,
                (__attribute__((address_space(3))) void*)&Bsl[(size_t)(it * 256 + wave * 64) * 8],
                16, 0, 0);
        }
        __syncthreads();

        bf16x8 af[4], bf[4];
#pragma unroll
        for (int mi = 0; mi < 4; mi++)
            af[mi] = *reinterpret_cast<const bf16x8*>(&Asl[(wm + mi * 16 + l16) * 32 + q * 8]);
#pragma unroll
        for (int ni = 0; ni < 4; ni++)
            bf[ni] = *reinterpret_cast<const bf16x8*>(&Bsl[(wn + ni * 16 + l16) * 32 + q * 8]);
#pragma unroll
        for (int mi = 0; mi < 4; mi++)
#pragma unroll
            for (int ni = 0; ni < 4; ni++)
                acc[mi][ni] = __builtin_amdgcn_mfma_f32_16x16x32_bf16(af[mi], bf[ni], acc[mi][ni], 0, 0, 0);
        __syncthreads();
    }

#pragma unroll
    for (int mi = 0; mi < 4; mi++) {
#pragma unroll
        for (int r = 0; r < 4; r++) {
            int grow = rowBase + wm + mi * 16 + q * 4 + r;
            if (grow < M) {
#pragma unroll
                for (int ni = 0; ni < 4; ni++) {
                    int gcol = colBase + wn + ni * 16 + l16;
                    C[(size_t)grow * N + gcol] = f2bf(acc[mi][ni][r]);
                }
            }
        }
    }
}

// ---------------- attention logits: one wave per node, bf16 h ----------------
template <int H, int C>
__global__ __launch_bounds__(256) void gat_alpha(const unsigned short* __restrict__ hb,
                                                 const float* __restrict__ a_src,
                                                 const float* __restrict__ a_dst,
                                                 float* __restrict__ alS,
                                                 float* __restrict__ alD, int N) {
    constexpr int HC = H * C;
    constexpr int PER = HC / 64;
    constexpr int LPH = C / PER;   // lanes per head
    int n = (blockIdx.x * blockDim.x + threadIdx.x) >> 6;
    int lane = threadIdx.x & 63;
    if (n >= N) return;
    const int myh = (lane * PER) / C;
    const int cc  = (lane * PER) % C;
    const unsigned short* hp = hb + (size_t)n * HC + lane * PER;

    float hv[PER];
    if (PER == 8) {
        uint4 raw = *reinterpret_cast<const uint4*>(hp);
        hv[0] = bf_lo(raw.x); hv[1] = bf_hi(raw.x);
        hv[2] = bf_lo(raw.y); hv[3] = bf_hi(raw.y);
        hv[4] = bf_lo(raw.z); hv[5] = bf_hi(raw.z);
        hv[6] = bf_lo(raw.w); hv[7] = bf_hi(raw.w);
    } else {
        unsigned raw = *reinterpret_cast<const unsigned*>(hp);
        hv[0] = bf_lo(raw); hv[1] = bf_hi(raw);
    }
    float s = 0.f, d = 0.f;
#pragma unroll
    for (int j = 0; j < PER; j++) {
        s += hv[j] * a_src[myh * C + cc + j];
        d += hv[j] * a_dst[myh * C + cc + j];
    }
#pragma unroll
    for (int dd = 1; dd < LPH; dd <<= 1) {
        s += __shfl_xor(s, dd);
        d += __shfl_xor(d, dd);
    }
    if ((lane & (LPH - 1)) == 0) {
        alS[n * H + myh] = s;
        alD[n * H + myh] = d;
    }
}

// ---------------- segment softmax + aggregate, one wave per dst node, bf16 h ----------
// Pass 2 uses 64-edge chunks: lane precomputes its edge's weights, inner loop
// broadcasts (readlane) src idx + weight and software-pipelines the h-row loads.
template <int H, int C, int OUT_BF16>
__global__ __launch_bounds__(256) void gat_aggregate(const unsigned short* __restrict__ hb,
                                                     const float* __restrict__ alS,
                                                     const float* __restrict__ alD,
                                                     const int* __restrict__ off,
                                                     const int* __restrict__ csr_src,
                                                     const float* __restrict__ bias,
                                                     void* __restrict__ outbuf,
                                                     int N, int do_relu) {
    constexpr int HC = H * C;
    constexpr int PER = HC / 64;
    int n = (blockIdx.x * blockDim.x + threadIdx.x) >> 6;
    int lane = threadIdx.x & 63;
    if (n >= N) return;
    int beg = off[n], end = off[n + 1];

    float ad[H];
#pragma unroll
    for (int h = 0; h < H; h++) ad[h] = alD[n * H + h];

    // pass 1: online softmax over edges (lanes strided)
    float m[H], den[H];
#pragma unroll
    for (int h = 0; h < H; h++) { m[h] = -1e30f; den[h] = 0.f; }
    for (int e = beg + lane; e < end; e += 64) {
        int s = csr_src[e];
        float av[H];
        if (H == 4) {
            float4 a4 = *reinterpret_cast<const float4*>(&alS[s * 4]);
            av[0] = a4.x; av[1] = a4.y; av[2] = a4.z; av[3] = a4.w;
        } else {
            av[0] = alS[s];
        }
#pragma unroll
        for (int h = 0; h < H; h++) {
            float v = lrelu(av[h] + ad[h]);
            float nm = fmaxf(m[h], v);
            den[h] = den[h] * __expf(m[h] - nm) + __expf(v - nm);
            m[h] = nm;
        }
    }
#pragma unroll
    for (int dd = 1; dd < 64; dd <<= 1) {
#pragma unroll
        for (int h = 0; h < H; h++) {
            float om = __shfl_xor(m[h], dd);
            float od = __shfl_xor(den[h], dd);
            float nm = fmaxf(m[h], om);
            den[h] = den[h] * __expf(m[h] - nm) + od * __expf(om - nm);
            m[h] = nm;
        }
    }
    float invh[H];
#pragma unroll
    for (int h = 0; h < H; h++) invh[h] = 1.f / den[h];

    const int myh = (lane * PER) / C;

    float acc[PER];
#pragma unroll
    for (int j = 0; j < PER; j++) acc[j] = 0.f;

    // pass 2: chunked, shfl-broadcast weights, depth-2 pipelined h loads
    for (int base = beg; base < end; base += 64) {
        int cnt = end - base; if (cnt > 64) cnt = 64;
        int s_l = csr_src[base + (lane < cnt ? lane : 0)];
        float wl[H];
        if (H == 4) {
            float4 a4 = *reinterpret_cast<const float4*>(&alS[s_l * 4]);
            wl[0] = __expf(lrelu(a4.x + ad[0]) - m[0]) * invh[0];
            wl[1] = __expf(lrelu(a4.y + ad[1]) - m[1]) * invh[1];
            wl[2] = __expf(lrelu(a4.z + ad[2]) - m[2]) * invh[2];
            wl[3] = __expf(lrelu(a4.w + ad[3]) - m[3]) * invh[3];
        } else {
            wl[0] = __expf(lrelu(alS[s_l] + ad[0]) - m[0]) * invh[0];
        }

        if (PER == 8) {
            uint4 raw; float wc;
            {   // prologue: fetch edge 0
                int s = __shfl(s_l, 0);
                float w0 = __shfl(wl[0], 0), w1 = __shfl(wl[1], 0),
                      w2 = __shfl(wl[2], 0), w3 = __shfl(wl[3], 0);
                wc = (myh & 2) ? ((myh & 1) ? w3 : w2) : ((myh & 1) ? w1 : w0);
                raw = *reinterpret_cast<const uint4*>(hb + (size_t)s * HC + lane * PER);
            }
            for (int i = 0; i < cnt; i++) {
                uint4 rc = raw; float w = wc;
                if (i + 1 < cnt) {
                    int s = __shfl(s_l, i + 1);
                    float w0 = __shfl(wl[0], i + 1), w1 = __shfl(wl[1], i + 1),
                          w2 = __shfl(wl[2], i + 1), w3 = __shfl(wl[3], i + 1);
                    wc = (myh & 2) ? ((myh & 1) ? w3 : w2) : ((myh & 1) ? w1 : w0);
                    raw = *reinterpret_cast<const uint4*>(hb + (size_t)s * HC + lane * PER);
                }
                acc[0] += bf_lo(rc.x) * w; acc[1] += bf_hi(rc.x) * w;
                acc[2] += bf_lo(rc.y) * w; acc[3] += bf_hi(rc.y) * w;
                acc[4] += bf_lo(rc.z) * w; acc[5] += bf_hi(rc.z) * w;
                acc[6] += bf_lo(rc.w) * w; acc[7] += bf_hi(rc.w) * w;
            }
        } else {
            unsigned raw; float wc;
            {
                int s = __shfl(s_l, 0);
                wc = __shfl(wl[0], 0);
                raw = *reinterpret_cast<const unsigned*>(hb + (size_t)s * HC + lane * PER);
            }
            for (int i = 0; i < cnt; i++) {
                unsigned rc = raw; float w = wc;
                if (i + 1 < cnt) {
                    int s = __shfl(s_l, i + 1);
                    wc = __shfl(wl[0], i + 1);
                    raw = *reinterpret_cast<const unsigned*>(hb + (size_t)s * HC + lane * PER);
                }
                acc[0] += bf_lo(rc) * w; acc[1] += bf_hi(rc) * w;
            }
        }
    }

#pragma unroll
    for (int j = 0; j < PER; j++) {
        int c = lane * PER + j;
        float v = acc[j] + bias[c];
        if (do_relu) v = fmaxf(v, 0.f);
        if (OUT_BF16) ((unsigned short*)outbuf)[(size_t)n * HC + c] = f2bf(v);
        else          ((float*)outbuf)[(size_t)n * HC + c] = v;
    }
}

// ---------------- risk head: shfl-broadcast, no serial global loads ----------------
__global__ __launch_bounds__(256) void head_kernel(const float* __restrict__ h3,
                                                   const float* __restrict__ Ws1,
                                                   const float* __restrict__ bs1,
                                                   const float* __restrict__ Ws2,
                                                   const float* __restrict__ bs2,
                                                   float* __restrict__ out, int N) {
    int n = (blockIdx.x * blockDim.x + threadIdx.x) >> 6;
    int lane = threadIdx.x & 63;
    if (n >= N) return;
    float2 h2 = *reinterpret_cast<const float2*>(h3 + (size_t)n * 128 + 2 * lane);
    float s0 = 0.f, s1 = 0.f;
#pragma unroll
    for (int k = 0; k < 64; k++) {
        float a = __shfl(h2.x, k);
        float b = __shfl(h2.y, k);
        s0 += a * Ws1[(2 * k) * 64 + lane];
        s1 += b * Ws1[(2 * k + 1) * 64 + lane];
    }
    float s = fmaxf(s0 + s1 + bs1[lane], 0.f);
    float z = s * Ws2[lane];
#pragma unroll
    for (int d = 1; d < 64; d <<= 1) z += __shfl_xor(z, d);
    if (lane == 0) out[n] = 1.f / (1.f + __expf(-(z + bs2[0])));
}

// ---------------- launch ----------------
extern "C" void kernel_launch(void* const* d_in, const int* in_sizes, int n_in,
                              void* d_out, int out_size, void* d_ws, size_t ws_size,
                              hipStream_t stream) {
    const float* x   = (const float*)d_in[0];
    const int*   ei  = (const int*)d_in[1];
    const float* W1  = (const float*)d_in[2];
    const float* as1 = (const float*)d_in[3];
    const float* ad1 = (const float*)d_in[4];
    const float* b1  = (const float*)d_in[5];
    const float* W2  = (const float*)d_in[6];
    const float* as2 = (const float*)d_in[7];
    const float* ad2 = (const float*)d_in[8];
    const float* b2  = (const float*)d_in[9];
    const float* W3  = (const float*)d_in[10];
    const float* as3 = (const float*)d_in[11];
    const float* ad3 = (const float*)d_in[12];
    const float* b3  = (const float*)d_in[13];
    const float* Ws1 = (const float*)d_in[14];
    const float* bs1 = (const float*)d_in[15];
    const float* Ws2 = (const float*)d_in[16];
    const float* bs2 = (const float*)d_in[17];

    const int N = out_size;            // 20000
    const int E = in_sizes[1] / 2;     // 160000
    const int D = in_sizes[0] / N;     // 768
    const int HC = 512, H = 4, C = 128;
    const int Etot = E + N;

    char* p = (char*)d_ws;
    auto alloc = [&](size_t bytes) -> void* {
        void* q = (void*)p;
        p += (bytes + 255) & ~(size_t)255;
        return q;
    };
    int*   deg    = (int*)alloc((size_t)N * 4);
    int*   off    = (int*)alloc((size_t)(N + 1) * 4);
    int*   cursor = (int*)alloc((size_t)N * 4);
    int*   csr    = (int*)alloc((size_t)Etot * 4);
    float* alS    = (float*)alloc((size_t)N * H * 4);
    float* alD    = (float*)alloc((size_t)N * H * 4);
    float* o3     = (float*)alloc((size_t)N * C * 4);
    unsigned short* hbuf = (unsigned short*)alloc((size_t)N * HC * 2);
    unsigned short* xbf  = (unsigned short*)alloc((size_t)N * D * 2);
    unsigned short* obf  = (unsigned short*)alloc((size_t)N * HC * 2);
    unsigned short* W1t  = (unsigned short*)alloc((size_t)D * HC * 2);
    unsigned short* W2t  = (unsigned short*)alloc((size_t)HC * HC * 2);
    unsigned short* W3t  = (unsigned short*)alloc((size_t)HC * C * 2);

    hipMemsetAsync(deg, 0, (size_t)N * 4, stream);
    hipMemsetAsync(cursor, 0, (size_t)N * 4, stream);

    const int tb = 256;
    count_deg_kernel<<<(Etot + tb - 1) / tb, tb, 0, stream>>>(ei, E, N, deg);
    scan_kernel<<<1, 1024, 0, stream>>>(deg, off, N);
    scatter_kernel<<<(Etot + tb - 1) / tb, tb, 0, stream>>>(ei, E, N, off, cursor, csr);

    {
        size_t n4 = (size_t)N * D / 4;
        cast_bf16_kernel<<<(int)((n4 + 255) / 256), 256, 0, stream>>>(x, xbf, n4);
        transpose_cast_kernel<<<(D * HC + 255) / 256, 256, 0, stream>>>(W1, W1t, D, HC);
        transpose_cast_kernel<<<(HC * HC + 255) / 256, 256, 0, stream>>>(W2, W2t, HC, HC);
        transpose_cast_kernel<<<(HC * C + 255) / 256, 256, 0, stream>>>(W3, W3t, HC, C);
    }

    int node_blocks = (N + 3) / 4;     // one wave per node
    int rowTiles = (N + 127) / 128;

    // ---- layer 1 ----
    gemm_bf16<<<dim3(HC / 128, rowTiles), 256, 0, stream>>>(xbf, W1t, hbuf, N, HC, D);
    gat_alpha<4, 128><<<node_blocks, 256, 0, stream>>>(hbuf, as1, ad1, alS, alD, N);
    gat_aggregate<4, 128, 1><<<node_blocks, 256, 0, stream>>>(hbuf, alS, alD, off, csr, b1, obf, N, 1);

    // ---- layer 2 ----
    gemm_bf16<<<dim3(HC / 128, rowTiles), 256, 0, stream>>>(obf, W2t, hbuf, N, HC, HC);
    gat_alpha<4, 128><<<node_blocks, 256, 0, stream>>>(hbuf, as2, ad2, alS, alD, N);
    gat_aggregate<4, 128, 1><<<node_blocks, 256, 0, stream>>>(hbuf, alS, alD, off, csr, b2, obf, N, 1);

    // ---- layer 3 (H=1, C=128) ----
    gemm_bf16<<<dim3(C / 128, rowTiles), 256, 0, stream>>>(obf, W3t, hbuf, N, C, HC);
    gat_alpha<1, 128><<<node_blocks, 256, 0, stream>>>(hbuf, as3, ad3, alS, alD, N);
    gat_aggregate<1, 128, 0><<<node_blocks, 256, 0, stream>>>(hbuf, alS, alD, off, csr, b3, o3, N, 0);

    // ---- head ----
    head_kernel<<<node_blocks, 256, 0, stream>>>(o3, Ws1, bs1, Ws2, bs2, (float*)d_out, N);
}